// Round 3
// baseline (688.782 us; speedup 1.0000x reference)
//
#include <hip/hip_runtime.h>
#include <math.h>

#define BATCH 16384
#define NCLS  8192
#define NTAIL 16

// ws layout: [0, 64KB)     p_true  (float[BATCH])
//            [64KB, 128KB) argmax  (int[BATCH])

// One block (256 threads = 4 waves) per row. Each thread holds its full
// 32-element slice in registers: load-all, branch-free max/argmax pass,
// then 32 independent exps. The label logit is grabbed from the register
// tile via LDS (no epilogue global re-read). No atomics: argmax is written
// per-row and counted by finish_kernel.
__global__ __launch_bounds__(256) void row_kernel(const float* __restrict__ x,
                                                  const int* __restrict__ labels,
                                                  float* __restrict__ p_true,
                                                  int* __restrict__ argmax_out) {
    const int row = blockIdx.x;
    const int t   = threadIdx.x;
    const float4* rowp = (const float4*)(x + (size_t)row * NCLS);
    const int lab = labels[row];          // wave-uniform scalar load

    float4 v[8];
    #pragma unroll
    for (int k = 0; k < 8; ++k) v[k] = rowp[t + k * 256];

    float e[32];
    #pragma unroll
    for (int k = 0; k < 8; ++k) {
        e[4 * k + 0] = v[k].x; e[4 * k + 1] = v[k].y;
        e[4 * k + 2] = v[k].z; e[4 * k + 3] = v[k].w;
    }
    #pragma unroll
    for (int i = 0; i < 32; ++i) e[i] = (e[i] == e[i]) ? e[i] : 0.0f;  // nan_to_num

    // Stash the (nan-fixed) label logit: float4-chunk q = lab>>2 is owned by
    // thread (q & 255), register slot (q>>8)*4 + (lab&3).
    __shared__ float s_xlab;
    {
        const int q = lab >> 2;
        if (t == (q & 255)) s_xlab = e[((q >> 8) << 2) + (lab & 3)];
    }

    // Pass 1: thread-local max + first-occurrence argmax. Column of e[i] is
    // (t + (i>>2)*256)*4 + (i&3) — ascending in i, so strict > keeps the
    // lowest column on ties.
    float m = e[0];
    int   idx = t * 4;
    #pragma unroll
    for (int i = 1; i < 32; ++i) {
        const int col = (t + (i >> 2) * 256) * 4 + (i & 3);
        if (e[i] > m) { m = e[i]; idx = col; }
    }

    // Pass 2: 32 independent exps, 4 accumulators for ILP.
    const float L2E = 1.4426950408889634f;
    float s0 = 0.f, s1 = 0.f, s2 = 0.f, s3 = 0.f;
    #pragma unroll
    for (int i = 0; i < 32; i += 4) {
        s0 += exp2f((e[i + 0] - m) * L2E);
        s1 += exp2f((e[i + 1] - m) * L2E);
        s2 += exp2f((e[i + 2] - m) * L2E);
        s3 += exp2f((e[i + 3] - m) * L2E);
    }
    float s = (s0 + s1) + (s2 + s3);

    // wave(64)-level reduce of (m, idx, s)
    #pragma unroll
    for (int off = 32; off; off >>= 1) {
        float m2 = __shfl_down(m, off);
        float s2r = __shfl_down(s, off);
        int   i2 = __shfl_down(idx, off);
        if (m2 > m)       { s = s * exp2f((m - m2) * L2E) + s2r; m = m2; idx = i2; }
        else if (m2 == m) { s += s2r; idx = min(idx, i2); }
        else              { s += s2r * exp2f((m2 - m) * L2E); }
    }

    __shared__ float sm[4], ss[4];
    __shared__ int   si[4];
    const int wave = t >> 6;
    if ((t & 63) == 0) { sm[wave] = m; ss[wave] = s; si[wave] = idx; }
    __syncthreads();

    if (t == 0) {
        for (int wgi = 1; wgi < 4; ++wgi) {
            float m2 = sm[wgi], s2r = ss[wgi]; int i2 = si[wgi];
            if (m2 > m)       { s = s * exp2f((m - m2) * L2E) + s2r; m = m2; idx = i2; }
            else if (m2 == m) { s += s2r; idx = min(idx, i2); }
            else              { s += s2r * exp2f((m2 - m) * L2E); }
        }
        p_true[row]     = exp2f((s_xlab - m) * L2E) / s;
        argmax_out[row] = idx;
    }
}

// Single block: build the 16 tail-class counts in LDS, then compute the
// weighted focal penalty sum and write the final scalar (no init kernel,
// no global atomics).
__global__ __launch_bounds__(1024) void finish_kernel(const float* __restrict__ p_true,
                                                      const int* __restrict__ argmax_in,
                                                      const int* __restrict__ labels,
                                                      const int* __restrict__ prev_counts,
                                                      float* __restrict__ out) {
    const int t = threadIdx.x;
    __shared__ int   cnt[NTAIL];
    __shared__ float wsum[16];
    if (t < NTAIL) cnt[t] = 0;
    __syncthreads();

    for (int i = t; i < BATCH; i += 1024) {
        const int am = argmax_in[i];
        if (am >= NCLS - NTAIL) atomicAdd(&cnt[am - (NCLS - NTAIL)], 1);
    }
    __syncthreads();

    float acc = 0.0f;
    for (int i = t; i < BATCH; i += 1024) {
        const float p  = p_true[i];
        const int  lab = labels[i];
        float w = 1.0f;
        if (lab >= NCLS - NTAIL) {
            const int prev = prev_counts[lab];
            const int curr = cnt[lab - (NCLS - NTAIL)];
            w = (prev > 0 && curr < prev) ? 4.0f
              : (prev > 0 && curr > prev) ? 2.0f
              : 3.0f;
        }
        acc += -logf(p + 1e-7f) * (1.0f - p) * w;
    }

    #pragma unroll
    for (int off = 32; off; off >>= 1) acc += __shfl_down(acc, off);
    if ((t & 63) == 0) wsum[t >> 6] = acc;
    __syncthreads();
    if (t == 0) {
        float s = 0.0f;
        #pragma unroll
        for (int w = 0; w < 16; ++w) s += wsum[w];
        out[0] = s * (0.1f / (float)BATCH);
    }
}

extern "C" void kernel_launch(void* const* d_in, const int* in_sizes, int n_in,
                              void* d_out, int out_size, void* d_ws, size_t ws_size,
                              hipStream_t stream) {
    const float* x           = (const float*)d_in[0];
    const int*   labels      = (const int*)  d_in[1];
    const int*   prev_counts = (const int*)  d_in[2];
    // d_in[3] (tail_mask) is deterministic: class >= NCLS-NTAIL — recomputed inline.

    float* out    = (float*)d_out;
    float* p_true = (float*)d_ws;
    int*   argmax = (int*)((char*)d_ws + BATCH * sizeof(float));

    row_kernel<<<BATCH, 256, 0, stream>>>(x, labels, p_true, argmax);
    finish_kernel<<<1, 1024, 0, stream>>>(p_true, argmax, labels, prev_counts, out);
}